// Round 11
// baseline (1104.451 us; speedup 1.0000x reference)
//
#include <hip/hip_runtime.h>
#include <cstdint>
#include <cstddef>

#define B_ 4
#define N_ 4096
#define D_ 1024
#define CAND 16
#define M_ (B_*N_)
#define MD_ ((size_t)M_ * D_)
#define DD_ ((size_t)D_ * D_)

typedef __attribute__((ext_vector_type(8))) short short8;
typedef __attribute__((ext_vector_type(4))) float floatx4;

// ---------------------------------------------------------------------------
// Static device-global scratch. Every buffer fully overwritten before first
// read on every call.
// Round-11: (a) qk split into separate Q/K dispatches (~112 us each) so the
// 112-224 us band of the profile becomes visible in top-5; (b) rescore+gather
// fused (weights via LDS, one dispatch fewer). Math bit-identical.
// ---------------------------------------------------------------------------
__device__ __align__(16) float          g_Qf[MD_];            // 64 MiB fp32 q
__device__ __align__(16) float          g_Kf[MD_];            // 64 MiB fp32 k
__device__ __align__(16) unsigned short g_Qb[MD_];            // 32 MiB bf16 q
__device__ __align__(16) unsigned short g_Kb[MD_];            // 32 MiB bf16 k
__device__ __align__(16) float          g_Vf[MD_];            // 64 MiB fp32 v
__device__ __align__(16) unsigned short g_AO[MD_];            // 32 MiB bf16 attn-out
__device__ __align__(16) unsigned short g_X0[MD_];            // 32 MiB bf16 X hi
__device__ __align__(16) unsigned short g_X1[MD_];            // 32 MiB bf16 X lo
__device__ __align__(16) unsigned short g_Wq0T[DD_];          // 2 MiB each (T)
__device__ __align__(16) unsigned short g_Wq1T[DD_];
__device__ __align__(16) unsigned short g_Wk0T[DD_];
__device__ __align__(16) unsigned short g_Wk1T[DD_];
__device__ __align__(16) unsigned short g_WvT[DD_];           // 2 MiB bf16
__device__ __align__(16) unsigned short g_WoT[DD_];           // 2 MiB bf16
__device__ __align__(16) float          g_S[(size_t)B_ * N_ * N_]; // 256 MiB scores
__device__ __align__(16) int            g_cand[(size_t)M_ * CAND];

__device__ __forceinline__ float b2f(unsigned short u){
  return __uint_as_float(((unsigned int)u) << 16);
}
__device__ __forceinline__ unsigned short f2b(float f){
  unsigned int b = __float_as_uint(f);
  b += 0x7fffu + ((b >> 16) & 1u);   // RNE
  return (unsigned short)(b >> 16);
}
// 2-term bf16 split: x ~= b2f(h0)+b2f(h1), residual ~2^-17 |x|.
__device__ __forceinline__ void split2(float x, unsigned short& h0,
                                       unsigned short& h1){
  h0 = f2b(x);
  float r1 = x - b2f(h0);   // exact (Sterbenz)
  h1 = f2b(r1);
}

// Async global->LDS, 16 B per lane. LDS dest must be wave-uniform base +
// lane*16. Completion guaranteed by the vmcnt(0) drain before s_barrier.
__device__ __forceinline__ void gl_lds16(const void* g, void* l){
  __builtin_amdgcn_global_load_lds(
      (const __attribute__((address_space(1))) unsigned int*)g,
      (__attribute__((address_space(3))) unsigned int*)l, 16, 0, 0);
}

// ---------------------------------------------------------------------------
// Transpose Wv, Wo (fp32 [k][n] -> bf16 [n][k]) for B^T-layout bf16 GEMM
// ---------------------------------------------------------------------------
__global__ __launch_bounds__(256)
void transpose2(const float* __restrict__ Wv, const float* __restrict__ Wo){
  __shared__ float tile[32][33];
  const float* src = blockIdx.z ? Wo : Wv;
  unsigned short* dst = blockIdx.z ? g_WoT : g_WvT;
  int tx = threadIdx.x, ty = threadIdx.y;
  int n0 = blockIdx.x * 32, k0 = blockIdx.y * 32;
  for (int r = ty; r < 32; r += 8) tile[r][tx] = src[(size_t)(k0 + r) * D_ + n0 + tx];
  __syncthreads();
  for (int r = ty; r < 32; r += 8) dst[(size_t)(n0 + r) * D_ + k0 + tx] = f2b(tile[tx][r]);
}

// ---------------------------------------------------------------------------
// Transpose + 2-way split Wq, Wk (fp32 [k][n] -> 2x bf16 [n][k])
// ---------------------------------------------------------------------------
__global__ __launch_bounds__(256)
void split_wT(const float* __restrict__ Wq, const float* __restrict__ Wk){
  __shared__ float tile[32][33];
  const float* src = blockIdx.z ? Wk : Wq;
  unsigned short* d0 = blockIdx.z ? g_Wk0T : g_Wq0T;
  unsigned short* d1 = blockIdx.z ? g_Wk1T : g_Wq1T;
  int tx = threadIdx.x, ty = threadIdx.y;
  int n0 = blockIdx.x * 32, k0 = blockIdx.y * 32;
  for (int r = ty; r < 32; r += 8) tile[r][tx] = src[(size_t)(k0 + r) * D_ + n0 + tx];
  __syncthreads();
  for (int r = ty; r < 32; r += 8){
    unsigned short h0, h1;
    split2(tile[tx][r], h0, h1);
    size_t o = (size_t)(n0 + r) * D_ + k0 + tx;
    d0[o] = h0; d1[o] = h1;
  }
}

// ---------------------------------------------------------------------------
// 2-way split of X into bf16 planes (elementwise, float4/thread).
// Grid: M_ blocks x 256 thr x 4 elem = MD_ elements exactly.
// ---------------------------------------------------------------------------
__global__ __launch_bounds__(256)
void split_x(const float* __restrict__ X){
  size_t i = ((size_t)blockIdx.x * 256 + threadIdx.x) * 4;
  if (i >= MD_) return;
  float4 x = *(const float4*)&X[i];
  ushort4 u0, u1;
  split2(x.x, u0.x, u1.x);
  split2(x.y, u0.y, u1.y);
  split2(x.z, u0.z, u1.z);
  split2(x.w, u0.w, u1.w);
  *(ushort4*)&g_X0[i] = u0;
  *(ushort4*)&g_X1[i] = u1;
}

// ---------------------------------------------------------------------------
// Q/K projection via 3-term split-bf16 MFMA GEMM (error ~1.2e-5 relative):
//   out = X @ W + bias;  acc += X0W1 + X1W0 + X0W0   [3 MFMAs / pair]
// BK=64 -> 96 MFMAs per barrier-pair; round-6-verified swizzle (conflicts 0).
// Round-11: Q and K are separate dispatches (observability; ~112 us each).
// Grid 1024, 1-D transposed linearization: A-slab shared by 8 consecutive.
// ---------------------------------------------------------------------------
__global__ __launch_bounds__(256, 2)
void qk_split_gemm(const float* __restrict__ bias, int which){
  int p = blockIdx.x;
  int lin = (p & 7) * 128 + (p >> 3);   // bijective: 1024 = 8 * 128
  int mt = lin >> 3;                    // m-tile, slow (A-slab shared by 8)
  int nt = lin & 7;

  const unsigned short* __restrict__ B0 = which ? g_Wk0T : g_Wq0T;
  const unsigned short* __restrict__ B1 = which ? g_Wk1T : g_Wq1T;
  float* __restrict__ outf = which ? g_Kf : g_Qf;
  unsigned short* __restrict__ outb = which ? g_Kb : g_Qb;

  __shared__ unsigned short __align__(16) As0[128 * 64];   // 16 KiB each
  __shared__ unsigned short __align__(16) As1[128 * 64];
  __shared__ unsigned short __align__(16) Bs0[128 * 64];
  __shared__ unsigned short __align__(16) Bs1[128 * 64];

  int tid = threadIdx.x;
  size_t m0 = (size_t)mt * 128;
  int n0 = nt * 128;
  int l = tid & 63, wid = tid >> 6;
  int wm = (wid >> 1) * 64, wn = (wid & 1) * 64;
  int quad = l >> 4, lr = l & 15;

  floatx4 acc[4][4];
  #pragma unroll
  for (int i = 0; i < 4; i++)
    #pragma unroll
    for (int j = 0; j < 4; j++) acc[i][j] = (floatx4)0.0f;

  for (int k0 = 0; k0 < D_; k0 += 64){
    #pragma unroll
    for (int c = 0; c < 4; c++){
      int d = c * 4096 + tid * 16;                    // linear dest byte in tile
      int rw = d >> 7;                                // row (128-B rows)
      int sc = ((d & 127) ^ ((rw & 7) << 4)) >> 1;    // swizzled source col (elems)
      size_t ao = (m0 + rw) * D_ + k0 + sc;
      size_t bo = (size_t)(n0 + rw) * D_ + k0 + sc;
      gl_lds16(&g_X0[ao], &As0[d >> 1]);
      gl_lds16(&g_X1[ao], &As1[d >> 1]);
      gl_lds16(&B0[bo], &Bs0[d >> 1]);
      gl_lds16(&B1[bo], &Bs1[d >> 1]);
    }
    __syncthreads();   // compiler emits vmcnt(0) drain before barrier
    #pragma unroll
    for (int kk = 0; kk < 2; kk++){
      short8 a0[4], a1[4], b0[4], b1[4];
      #pragma unroll
      for (int i = 0; i < 4; i++){
        int rw = wm + i * 16 + lr;
        int byt = rw * 128 + ((kk * 64 + quad * 16) ^ ((rw & 7) << 4));
        a0[i] = *(const short8*)&As0[byt >> 1];
        a1[i] = *(const short8*)&As1[byt >> 1];
      }
      #pragma unroll
      for (int j = 0; j < 4; j++){
        int rw = wn + j * 16 + lr;
        int byt = rw * 128 + ((kk * 64 + quad * 16) ^ ((rw & 7) << 4));
        b0[j] = *(const short8*)&Bs0[byt >> 1];
        b1[j] = *(const short8*)&Bs1[byt >> 1];
      }
      // order-1 (small, ~2^-8) terms first, then the dominant hi*hi
      #pragma unroll
      for (int i = 0; i < 4; i++)
        #pragma unroll
        for (int j = 0; j < 4; j++){
          acc[i][j] = __builtin_amdgcn_mfma_f32_16x16x32_bf16(a0[i], b1[j], acc[i][j], 0, 0, 0);
          acc[i][j] = __builtin_amdgcn_mfma_f32_16x16x32_bf16(a1[i], b0[j], acc[i][j], 0, 0, 0);
          acc[i][j] = __builtin_amdgcn_mfma_f32_16x16x32_bf16(a0[i], b0[j], acc[i][j], 0, 0, 0);
        }
    }
    __syncthreads();
  }
  // C/D layout (m89-verified): col = lane&15, row = quad*4 + reg
  #pragma unroll
  for (int i = 0; i < 4; i++)
    #pragma unroll
    for (int j = 0; j < 4; j++)
      #pragma unroll
      for (int rg = 0; rg < 4; rg++){
        size_t row = m0 + wm + i * 16 + quad * 4 + rg;
        int col = n0 + wn + j * 16 + lr;
        float val = acc[i][j][rg] + bias[col];
        outf[row * D_ + col] = val;
        outb[row * D_ + col] = f2b(val);
      }
}

// ---------------------------------------------------------------------------
// bf16 MFMA GEMM: C = A @ Bt^T + bias, fp32 out. BK=128, swizzled
// (64 MFMAs per barrier-pair per wave; 256-B rows, byte ^= (row&7)<<4).
// sel==0: A=g_X0, Bt=g_WvT, C=g_Vf; sel==1: A=g_AO, Bt=g_WoT, C=Cout.
// ---------------------------------------------------------------------------
__global__ __launch_bounds__(256, 2)
void gemm_bf16(const float* __restrict__ bias, float* __restrict__ Cout, int sel){
  const unsigned short* Asrc = sel ? g_AO : g_X0;
  const unsigned short* Bt = sel ? g_WoT : g_WvT;
  float* C = sel ? Cout : g_Vf;
  __shared__ unsigned short __align__(16) As[128 * 128];   // 32 KiB
  __shared__ unsigned short __align__(16) Bs[128 * 128];   // 32 KiB
  int p = blockIdx.x;
  int lin = (p & 7) * 128 + (p >> 3);   // bijective: 1024 = 8 * 128
  int mt = lin >> 3;
  int nt = lin & 7;
  int tid = threadIdx.x;
  size_t m0 = (size_t)mt * 128;
  int n0 = nt * 128;
  int l = tid & 63, wid = tid >> 6;
  int wm = (wid >> 1) * 64, wn = (wid & 1) * 64;
  int quad = l >> 4, lr = l & 15;
  floatx4 acc[4][4];
  #pragma unroll
  for (int i = 0; i < 4; i++)
    #pragma unroll
    for (int j = 0; j < 4; j++) acc[i][j] = (floatx4)0.0f;

  for (int k0 = 0; k0 < D_; k0 += 128){
    #pragma unroll
    for (int c = 0; c < 8; c++){
      int d = c * 4096 + tid * 16;                    // linear dest byte in tile
      int rw = d >> 8;                                // row (256-B rows)
      int sc = ((d & 255) ^ ((rw & 7) << 4)) >> 1;    // swizzled source col (elems)
      gl_lds16(&Asrc[(m0 + rw) * D_ + k0 + sc], &As[d >> 1]);
      gl_lds16(&Bt[(size_t)(n0 + rw) * D_ + k0 + sc], &Bs[d >> 1]);
    }
    __syncthreads();
    #pragma unroll
    for (int kk = 0; kk < 4; kk++){
      short8 af[4], bf[4];
      #pragma unroll
      for (int i = 0; i < 4; i++){
        int rw = wm + i * 16 + lr;
        int byt = rw * 256 + ((kk * 64 + quad * 16) ^ ((rw & 7) << 4));
        af[i] = *(const short8*)&As[byt >> 1];
      }
      #pragma unroll
      for (int j = 0; j < 4; j++){
        int rw = wn + j * 16 + lr;
        int byt = rw * 256 + ((kk * 64 + quad * 16) ^ ((rw & 7) << 4));
        bf[j] = *(const short8*)&Bs[byt >> 1];
      }
      #pragma unroll
      for (int i = 0; i < 4; i++)
        #pragma unroll
        for (int j = 0; j < 4; j++)
          acc[i][j] = __builtin_amdgcn_mfma_f32_16x16x32_bf16(af[i], bf[j], acc[i][j], 0, 0, 0);
    }
    __syncthreads();
  }
  #pragma unroll
  for (int i = 0; i < 4; i++)
    #pragma unroll
    for (int j = 0; j < 4; j++)
      #pragma unroll
      for (int rg = 0; rg < 4; rg++){
        size_t row = m0 + wm + i * 16 + quad * 4 + rg;
        int col = n0 + wn + j * 16 + lr;
        C[row * D_ + col] = acc[i][j][rg] + bias[col];
      }
}

// ---------------------------------------------------------------------------
// Causal score tiles: S[b][i][j] = (q_i . k_j)/32, fp32, 128x128 tiles.
// Grid (32, 32, 4) = (jt, it, b); jt > it exits early. Diagonal masks j > i.
// BK=128 + swizzle (round-10).
// ---------------------------------------------------------------------------
__global__ __launch_bounds__(256, 2)
void scores_gemm(){
  int jt = blockIdx.x, it = blockIdx.y, b = blockIdx.z;
  if (jt > it) return;
  __shared__ unsigned short __align__(16) As[128 * 128];   // 32 KiB
  __shared__ unsigned short __align__(16) Bs[128 * 128];   // 32 KiB
  int tid = threadIdx.x;
  size_t am0 = (size_t)b * N_ + it * 128;   // Q rows (global)
  size_t bn0 = (size_t)b * N_ + jt * 128;   // K rows (global)
  int l = tid & 63, wid = tid >> 6;
  int wm = (wid >> 1) * 64, wn = (wid & 1) * 64;
  int quad = l >> 4, lr = l & 15;
  floatx4 acc[4][4];
  #pragma unroll
  for (int i = 0; i < 4; i++)
    #pragma unroll
    for (int j = 0; j < 4; j++) acc[i][j] = (floatx4)0.0f;

  for (int k0 = 0; k0 < D_; k0 += 128){
    #pragma unroll
    for (int c = 0; c < 8; c++){
      int d = c * 4096 + tid * 16;
      int rw = d >> 8;
      int sc = ((d & 255) ^ ((rw & 7) << 4)) >> 1;
      gl_lds16(&g_Qb[(am0 + rw) * D_ + k0 + sc], &As[d >> 1]);
      gl_lds16(&g_Kb[(bn0 + rw) * D_ + k0 + sc], &Bs[d >> 1]);
    }
    __syncthreads();
    #pragma unroll
    for (int kk = 0; kk < 4; kk++){
      short8 af[4], bf[4];
      #pragma unroll
      for (int i = 0; i < 4; i++){
        int rw = wm + i * 16 + lr;
        int byt = rw * 256 + ((kk * 64 + quad * 16) ^ ((rw & 7) << 4));
        af[i] = *(const short8*)&As[byt >> 1];
      }
      #pragma unroll
      for (int j = 0; j < 4; j++){
        int rw = wn + j * 16 + lr;
        int byt = rw * 256 + ((kk * 64 + quad * 16) ^ ((rw & 7) << 4));
        bf[j] = *(const short8*)&Bs[byt >> 1];
      }
      #pragma unroll
      for (int i = 0; i < 4; i++)
        #pragma unroll
        for (int j = 0; j < 4; j++)
          acc[i][j] = __builtin_amdgcn_mfma_f32_16x16x32_bf16(af[i], bf[j], acc[i][j], 0, 0, 0);
    }
    __syncthreads();
  }
  #pragma unroll
  for (int i = 0; i < 4; i++)
    #pragma unroll
    for (int j = 0; j < 4; j++)
      #pragma unroll
      for (int rg = 0; rg < 4; rg++){
        int row = it * 128 + wm + i * 16 + quad * 4 + rg;   // in-batch
        int col = jt * 128 + wn + j * 16 + lr;
        float v = acc[i][j][rg] * 0.03125f;
        if (col > row) v = -3.0e38f;
        g_S[((size_t)b * N_ + row) * N_ + col] = v;
      }
}

// ---------------------------------------------------------------------------
// Per-row top-16 of causal scores. One wave per row (4 rows/block).
// ---------------------------------------------------------------------------
__global__ __launch_bounds__(256)
void row_topk(){
  __shared__ float lv[CAND * 256];   // [u][wave*64+lane]
  __shared__ int   li[CAND * 256];
  int w = threadIdx.x >> 6, l = threadIdx.x & 63;
  int g = threadIdx.x;
  int i = blockIdx.x * 4 + w;               // global row
  int irow = i & (N_ - 1);                  // in-batch row
  const float* Srow = &g_S[(size_t)i * N_];
  #pragma unroll
  for (int u = 0; u < CAND; u++){ lv[u * 256 + g] = -3.0e38f; li[u * 256 + g] = -1; }
  float vmin = -3.0e38f; int pmin = 0;
  for (int j0 = l * 4; j0 <= irow; j0 += 256){
    float4 v4 = *(const float4*)&Srow[j0];
    #pragma unroll
    for (int e = 0; e < 4; e++){
      float v = (&v4.x)[e];
      if (v > vmin){
        lv[pmin * 256 + g] = v; li[pmin * 256 + g] = j0 + e;
        float m = lv[g]; int p = 0;
        #pragma unroll
        for (int u = 1; u < CAND; u++){ float x = lv[u * 256 + g]; if (x < m){ m = x; p = u; } }
        vmin = m; pmin = p;
      }
    }
  }
  float mv = lv[g]; int mp = 0;
  #pragma unroll
  for (int u = 1; u < CAND; u++){ float x = lv[u * 256 + g]; if (x > mv){ mv = x; mp = u; } }
  int mj = li[mp * 256 + g];
  for (int rd = 0; rd < CAND; rd++){
    float bv = mv; int bj = mj; int bl = l;
    #pragma unroll
    for (int off = 32; off >= 1; off >>= 1){
      float ov = __shfl_xor(bv, off);
      int oj = __shfl_xor(bj, off);
      int ol = __shfl_xor(bl, off);
      if (ov > bv || (ov == bv && ol < bl)){ bv = ov; bj = oj; bl = ol; }
    }
    bool valid = (bv > -2.9e38f);
    if (l == 0) g_cand[(size_t)i * CAND + rd] = valid ? bj : -1;
    if (valid && bl == l){
      lv[mp * 256 + g] = -3.0e38f;
      mv = lv[g]; mp = 0;
      #pragma unroll
      for (int u = 1; u < CAND; u++){ float x = lv[u * 256 + g]; if (x > mv){ mv = x; mp = u; } }
      mj = li[mp * 256 + g];
    }
  }
}

// ---------------------------------------------------------------------------
// Fused: fp64 rescore of 16 candidates -> top-8 + softmax weights (in LDS)
// -> attn_out[i] = sum_r w_r * v[idx_r] (fp32 accumulate, bf16 out).
// Identical math to the old rescore_top8 + gather_v pair; weights/indices
// pass through LDS instead of a global round-trip.
// ---------------------------------------------------------------------------
__global__ __launch_bounds__(256)
void rescore_gather(){
  int i = blockIdx.x;
  int b = i >> 12;
  int tid = threadIdx.x, l = tid & 63, w = tid >> 6;
  __shared__ double cs[CAND];
  __shared__ int cid[CAND];
  __shared__ float ws8[8];
  __shared__ int id8[8];
  if (tid < CAND) cid[tid] = g_cand[(size_t)i * CAND + tid];
  __syncthreads();
  double q[16];
  #pragma unroll
  for (int u = 0; u < 16; u++) q[u] = (double)g_Qf[(size_t)i * D_ + l + 64 * u];
  for (int c = w * 4; c < w * 4 + 4; c++){
    int j = cid[c];
    double s = 0.0;
    if (j >= 0){
      size_t ko = ((size_t)(b * N_ + j)) * D_;
      #pragma unroll
      for (int u = 0; u < 16; u++) s = fma(q[u], (double)g_Kf[ko + l + 64 * u], s);
    }
    #pragma unroll
    for (int off = 32; off >= 1; off >>= 1) s += __shfl_down(s, off);
    if (l == 0) cs[c] = (j >= 0) ? s * 0.03125 : -1.0e300;
  }
  __syncthreads();
  if (tid == 0){
    double v8[8]; int i8[8];
    bool used[CAND];
    for (int u = 0; u < CAND; u++) used[u] = false;
    for (int rk = 0; rk < 8; rk++){
      double best = -1.0e300; int bp = -1;
      for (int c = 0; c < CAND; c++)
        if (!used[c] && cid[c] >= 0 && cs[c] > best){ best = cs[c]; bp = c; }
      if (bp >= 0){ used[bp] = true; v8[rk] = best; i8[rk] = cid[bp]; }
      else { v8[rk] = -1.0e300; i8[rk] = -1; }
    }
    if (i8[0] < 0){ i8[0] = i & (N_ - 1); v8[0] = 0.0; }   // never expected
    double mx = v8[0];
    double e[8]; double Z = 0.0;
    for (int rk = 0; rk < 8; rk++){
      e[rk] = (i8[rk] >= 0) ? exp(v8[rk] - mx) : 0.0;
      Z += e[rk];
    }
    for (int rk = 0; rk < 8; rk++){
      id8[rk] = i8[rk];
      ws8[rk] = (float)(e[rk] / Z);
    }
  }
  __syncthreads();
  int d0 = tid * 4;
  float a0 = 0.f, a1 = 0.f, a2 = 0.f, a3 = 0.f;
  #pragma unroll
  for (int rk = 0; rk < 8; rk++){
    int j = id8[rk];
    if (j < 0) continue;
    float wgt = ws8[rk];
    float4 vv = *(const float4*)&g_Vf[((size_t)(b * N_ + j)) * D_ + d0];
    a0 += wgt * vv.x; a1 += wgt * vv.y; a2 += wgt * vv.z; a3 += wgt * vv.w;
  }
  ushort4 o;
  o.x = f2b(a0); o.y = f2b(a1); o.z = f2b(a2); o.w = f2b(a3);
  *(ushort4*)&g_AO[(size_t)i * D_ + d0] = o;
}

// ---------------------------------------------------------------------------
extern "C" void kernel_launch(void* const* d_in, const int* in_sizes, int n_in,
                              void* d_out, int out_size, void* d_ws, size_t ws_size,
                              hipStream_t stream){
  const float* S  = (const float*)d_in[0];
  const float* Wq = (const float*)d_in[1];
  const float* bq = (const float*)d_in[2];
  const float* Wk = (const float*)d_in[3];
  const float* bk = (const float*)d_in[4];
  const float* Wv = (const float*)d_in[5];
  const float* bv = (const float*)d_in[6];
  const float* Wo = (const float*)d_in[7];
  const float* bo = (const float*)d_in[8];
  float* out = (float*)d_out;
  (void)d_ws; (void)ws_size; (void)in_sizes; (void)n_in; (void)out_size;

  transpose2<<<dim3(32, 32, 2), dim3(32, 8), 0, stream>>>(Wv, Wo);
  split_wT<<<dim3(32, 32, 2), dim3(32, 8), 0, stream>>>(Wq, Wk);
  split_x<<<dim3(M_), 256, 0, stream>>>(S);   // M_ blocks * 1024 elems = MD_
  qk_split_gemm<<<dim3(1024), 256, 0, stream>>>(bq, 0);
  qk_split_gemm<<<dim3(1024), 256, 0, stream>>>(bk, 1);
  gemm_bf16<<<dim3(1024), 256, 0, stream>>>(bv, nullptr, 0);
  scores_gemm<<<dim3(32, 32, 4), 256, 0, stream>>>();
  row_topk<<<dim3(M_ / 4), 256, 0, stream>>>();
  rescore_gather<<<dim3(M_), 256, 0, stream>>>();
  gemm_bf16<<<dim3(1024), 256, 0, stream>>>(bo, out, 1);
}

// Round 12
// 963.343 us; speedup vs baseline: 1.1465x; 1.1465x over previous
//
#include <hip/hip_runtime.h>
#include <cstdint>
#include <cstddef>

#define B_ 4
#define N_ 4096
#define D_ 1024
#define CAND 12
#define M_ (B_*N_)
#define MD_ ((size_t)M_ * D_)
#define DD_ ((size_t)D_ * D_)

typedef __attribute__((ext_vector_type(8))) short short8;
typedef __attribute__((ext_vector_type(4))) float floatx4;

// ---------------------------------------------------------------------------
// Static device-global scratch. Every buffer fully overwritten before first
// read on every call.
// Round-12: (a) qk re-fused (round-10 form, 225 us measured; the Q/K split
// double-read X); (b) rescore: CAND 16->12 (true top-8 is within bf16-top-12
// by a 30-80x error margin), fp32 dot (noise 5e-6 < 1.2e-5 method error),
// 3-candidate interleaved loads for ILP.
// ---------------------------------------------------------------------------
__device__ __align__(16) float          g_Qf[MD_];            // 64 MiB fp32 q
__device__ __align__(16) float          g_Kf[MD_];            // 64 MiB fp32 k
__device__ __align__(16) unsigned short g_Qb[MD_];            // 32 MiB bf16 q
__device__ __align__(16) unsigned short g_Kb[MD_];            // 32 MiB bf16 k
__device__ __align__(16) float          g_Vf[MD_];            // 64 MiB fp32 v
__device__ __align__(16) unsigned short g_AO[MD_];            // 32 MiB bf16 attn-out
__device__ __align__(16) unsigned short g_X0[MD_];            // 32 MiB bf16 X hi
__device__ __align__(16) unsigned short g_X1[MD_];            // 32 MiB bf16 X lo
__device__ __align__(16) unsigned short g_Wq0T[DD_];          // 2 MiB each (T)
__device__ __align__(16) unsigned short g_Wq1T[DD_];
__device__ __align__(16) unsigned short g_Wk0T[DD_];
__device__ __align__(16) unsigned short g_Wk1T[DD_];
__device__ __align__(16) unsigned short g_WvT[DD_];           // 2 MiB bf16
__device__ __align__(16) unsigned short g_WoT[DD_];           // 2 MiB bf16
__device__ __align__(16) float          g_S[(size_t)B_ * N_ * N_]; // 256 MiB scores
__device__ __align__(16) int            g_cand[(size_t)M_ * CAND];

__device__ __forceinline__ float b2f(unsigned short u){
  return __uint_as_float(((unsigned int)u) << 16);
}
__device__ __forceinline__ unsigned short f2b(float f){
  unsigned int b = __float_as_uint(f);
  b += 0x7fffu + ((b >> 16) & 1u);   // RNE
  return (unsigned short)(b >> 16);
}
// 2-term bf16 split: x ~= b2f(h0)+b2f(h1), residual ~2^-17 |x|.
__device__ __forceinline__ void split2(float x, unsigned short& h0,
                                       unsigned short& h1){
  h0 = f2b(x);
  float r1 = x - b2f(h0);   // exact (Sterbenz)
  h1 = f2b(r1);
}

// Async global->LDS, 16 B per lane. LDS dest must be wave-uniform base +
// lane*16. Completion guaranteed by the vmcnt(0) drain before s_barrier.
__device__ __forceinline__ void gl_lds16(const void* g, void* l){
  __builtin_amdgcn_global_load_lds(
      (const __attribute__((address_space(1))) unsigned int*)g,
      (__attribute__((address_space(3))) unsigned int*)l, 16, 0, 0);
}

// ---------------------------------------------------------------------------
// Transpose Wv, Wo (fp32 [k][n] -> bf16 [n][k]) for B^T-layout bf16 GEMM
// ---------------------------------------------------------------------------
__global__ __launch_bounds__(256)
void transpose2(const float* __restrict__ Wv, const float* __restrict__ Wo){
  __shared__ float tile[32][33];
  const float* src = blockIdx.z ? Wo : Wv;
  unsigned short* dst = blockIdx.z ? g_WoT : g_WvT;
  int tx = threadIdx.x, ty = threadIdx.y;
  int n0 = blockIdx.x * 32, k0 = blockIdx.y * 32;
  for (int r = ty; r < 32; r += 8) tile[r][tx] = src[(size_t)(k0 + r) * D_ + n0 + tx];
  __syncthreads();
  for (int r = ty; r < 32; r += 8) dst[(size_t)(n0 + r) * D_ + k0 + tx] = f2b(tile[tx][r]);
}

// ---------------------------------------------------------------------------
// Transpose + 2-way split Wq, Wk (fp32 [k][n] -> 2x bf16 [n][k])
// ---------------------------------------------------------------------------
__global__ __launch_bounds__(256)
void split_wT(const float* __restrict__ Wq, const float* __restrict__ Wk){
  __shared__ float tile[32][33];
  const float* src = blockIdx.z ? Wk : Wq;
  unsigned short* d0 = blockIdx.z ? g_Wk0T : g_Wq0T;
  unsigned short* d1 = blockIdx.z ? g_Wk1T : g_Wq1T;
  int tx = threadIdx.x, ty = threadIdx.y;
  int n0 = blockIdx.x * 32, k0 = blockIdx.y * 32;
  for (int r = ty; r < 32; r += 8) tile[r][tx] = src[(size_t)(k0 + r) * D_ + n0 + tx];
  __syncthreads();
  for (int r = ty; r < 32; r += 8){
    unsigned short h0, h1;
    split2(tile[tx][r], h0, h1);
    size_t o = (size_t)(n0 + r) * D_ + k0 + tx;
    d0[o] = h0; d1[o] = h1;
  }
}

// ---------------------------------------------------------------------------
// 2-way split of X into bf16 planes (elementwise, float4/thread).
// Grid: M_ blocks x 256 thr x 4 elem = MD_ elements exactly.
// ---------------------------------------------------------------------------
__global__ __launch_bounds__(256)
void split_x(const float* __restrict__ X){
  size_t i = ((size_t)blockIdx.x * 256 + threadIdx.x) * 4;
  if (i >= MD_) return;
  float4 x = *(const float4*)&X[i];
  ushort4 u0, u1;
  split2(x.x, u0.x, u1.x);
  split2(x.y, u0.y, u1.y);
  split2(x.z, u0.z, u1.z);
  split2(x.w, u0.w, u1.w);
  *(ushort4*)&g_X0[i] = u0;
  *(ushort4*)&g_X1[i] = u1;
}

// ---------------------------------------------------------------------------
// Q/K projection via 3-term split-bf16 MFMA GEMM (error ~1.2e-5 relative):
//   out = X @ W + bias;  acc += X0W1 + X1W0 + X0W0   [3 MFMAs / pair]
// BK=64 -> 96 MFMAs per barrier-pair; round-6-verified swizzle (conflicts 0).
// Fused Q+K (round-10 form, measured 225 us): grid 2048, 1-D transposed
// linearization so the 16 blocks (8 n x 2 which) sharing an A-slab are
// consecutive dispatches.
// ---------------------------------------------------------------------------
__global__ __launch_bounds__(256, 2)
void qk_split_gemm(const float* __restrict__ bq, const float* __restrict__ bk){
  int p = blockIdx.x;
  int lin = (p & 7) * 256 + (p >> 3);   // bijective: 2048 = 8 * 256
  int mt = lin >> 4;                    // m-tile, slow (A-slab shared by 16)
  int sub = lin & 15;
  int which = sub >> 3;
  int nt = sub & 7;

  const unsigned short* __restrict__ B0 = which ? g_Wk0T : g_Wq0T;
  const unsigned short* __restrict__ B1 = which ? g_Wk1T : g_Wq1T;
  const float* __restrict__ bias = which ? bk : bq;
  float* __restrict__ outf = which ? g_Kf : g_Qf;
  unsigned short* __restrict__ outb = which ? g_Kb : g_Qb;

  __shared__ unsigned short __align__(16) As0[128 * 64];   // 16 KiB each
  __shared__ unsigned short __align__(16) As1[128 * 64];
  __shared__ unsigned short __align__(16) Bs0[128 * 64];
  __shared__ unsigned short __align__(16) Bs1[128 * 64];

  int tid = threadIdx.x;
  size_t m0 = (size_t)mt * 128;
  int n0 = nt * 128;
  int l = tid & 63, wid = tid >> 6;
  int wm = (wid >> 1) * 64, wn = (wid & 1) * 64;
  int quad = l >> 4, lr = l & 15;

  floatx4 acc[4][4];
  #pragma unroll
  for (int i = 0; i < 4; i++)
    #pragma unroll
    for (int j = 0; j < 4; j++) acc[i][j] = (floatx4)0.0f;

  for (int k0 = 0; k0 < D_; k0 += 64){
    #pragma unroll
    for (int c = 0; c < 4; c++){
      int d = c * 4096 + tid * 16;                    // linear dest byte in tile
      int rw = d >> 7;                                // row (128-B rows)
      int sc = ((d & 127) ^ ((rw & 7) << 4)) >> 1;    // swizzled source col (elems)
      size_t ao = (m0 + rw) * D_ + k0 + sc;
      size_t bo = (size_t)(n0 + rw) * D_ + k0 + sc;
      gl_lds16(&g_X0[ao], &As0[d >> 1]);
      gl_lds16(&g_X1[ao], &As1[d >> 1]);
      gl_lds16(&B0[bo], &Bs0[d >> 1]);
      gl_lds16(&B1[bo], &Bs1[d >> 1]);
    }
    __syncthreads();   // compiler emits vmcnt(0) drain before barrier
    #pragma unroll
    for (int kk = 0; kk < 2; kk++){
      short8 a0[4], a1[4], b0[4], b1[4];
      #pragma unroll
      for (int i = 0; i < 4; i++){
        int rw = wm + i * 16 + lr;
        int byt = rw * 128 + ((kk * 64 + quad * 16) ^ ((rw & 7) << 4));
        a0[i] = *(const short8*)&As0[byt >> 1];
        a1[i] = *(const short8*)&As1[byt >> 1];
      }
      #pragma unroll
      for (int j = 0; j < 4; j++){
        int rw = wn + j * 16 + lr;
        int byt = rw * 128 + ((kk * 64 + quad * 16) ^ ((rw & 7) << 4));
        b0[j] = *(const short8*)&Bs0[byt >> 1];
        b1[j] = *(const short8*)&Bs1[byt >> 1];
      }
      // order-1 (small, ~2^-8) terms first, then the dominant hi*hi
      #pragma unroll
      for (int i = 0; i < 4; i++)
        #pragma unroll
        for (int j = 0; j < 4; j++){
          acc[i][j] = __builtin_amdgcn_mfma_f32_16x16x32_bf16(a0[i], b1[j], acc[i][j], 0, 0, 0);
          acc[i][j] = __builtin_amdgcn_mfma_f32_16x16x32_bf16(a1[i], b0[j], acc[i][j], 0, 0, 0);
          acc[i][j] = __builtin_amdgcn_mfma_f32_16x16x32_bf16(a0[i], b0[j], acc[i][j], 0, 0, 0);
        }
    }
    __syncthreads();
  }
  // C/D layout (m89-verified): col = lane&15, row = quad*4 + reg
  #pragma unroll
  for (int i = 0; i < 4; i++)
    #pragma unroll
    for (int j = 0; j < 4; j++)
      #pragma unroll
      for (int rg = 0; rg < 4; rg++){
        size_t row = m0 + wm + i * 16 + quad * 4 + rg;
        int col = n0 + wn + j * 16 + lr;
        float val = acc[i][j][rg] + bias[col];
        outf[row * D_ + col] = val;
        outb[row * D_ + col] = f2b(val);
      }
}

// ---------------------------------------------------------------------------
// bf16 MFMA GEMM: C = A @ Bt^T + bias, fp32 out. BK=128, swizzled
// (64 MFMAs per barrier-pair per wave; 256-B rows, byte ^= (row&7)<<4).
// sel==0: A=g_X0, Bt=g_WvT, C=g_Vf; sel==1: A=g_AO, Bt=g_WoT, C=Cout.
// ---------------------------------------------------------------------------
__global__ __launch_bounds__(256, 2)
void gemm_bf16(const float* __restrict__ bias, float* __restrict__ Cout, int sel){
  const unsigned short* Asrc = sel ? g_AO : g_X0;
  const unsigned short* Bt = sel ? g_WoT : g_WvT;
  float* C = sel ? Cout : g_Vf;
  __shared__ unsigned short __align__(16) As[128 * 128];   // 32 KiB
  __shared__ unsigned short __align__(16) Bs[128 * 128];   // 32 KiB
  int p = blockIdx.x;
  int lin = (p & 7) * 128 + (p >> 3);   // bijective: 1024 = 8 * 128
  int mt = lin >> 3;
  int nt = lin & 7;
  int tid = threadIdx.x;
  size_t m0 = (size_t)mt * 128;
  int n0 = nt * 128;
  int l = tid & 63, wid = tid >> 6;
  int wm = (wid >> 1) * 64, wn = (wid & 1) * 64;
  int quad = l >> 4, lr = l & 15;
  floatx4 acc[4][4];
  #pragma unroll
  for (int i = 0; i < 4; i++)
    #pragma unroll
    for (int j = 0; j < 4; j++) acc[i][j] = (floatx4)0.0f;

  for (int k0 = 0; k0 < D_; k0 += 128){
    #pragma unroll
    for (int c = 0; c < 8; c++){
      int d = c * 4096 + tid * 16;                    // linear dest byte in tile
      int rw = d >> 8;                                // row (256-B rows)
      int sc = ((d & 255) ^ ((rw & 7) << 4)) >> 1;    // swizzled source col (elems)
      gl_lds16(&Asrc[(m0 + rw) * D_ + k0 + sc], &As[d >> 1]);
      gl_lds16(&Bt[(size_t)(n0 + rw) * D_ + k0 + sc], &Bs[d >> 1]);
    }
    __syncthreads();
    #pragma unroll
    for (int kk = 0; kk < 4; kk++){
      short8 af[4], bf[4];
      #pragma unroll
      for (int i = 0; i < 4; i++){
        int rw = wm + i * 16 + lr;
        int byt = rw * 256 + ((kk * 64 + quad * 16) ^ ((rw & 7) << 4));
        af[i] = *(const short8*)&As[byt >> 1];
      }
      #pragma unroll
      for (int j = 0; j < 4; j++){
        int rw = wn + j * 16 + lr;
        int byt = rw * 256 + ((kk * 64 + quad * 16) ^ ((rw & 7) << 4));
        bf[j] = *(const short8*)&Bs[byt >> 1];
      }
      #pragma unroll
      for (int i = 0; i < 4; i++)
        #pragma unroll
        for (int j = 0; j < 4; j++)
          acc[i][j] = __builtin_amdgcn_mfma_f32_16x16x32_bf16(af[i], bf[j], acc[i][j], 0, 0, 0);
    }
    __syncthreads();
  }
  #pragma unroll
  for (int i = 0; i < 4; i++)
    #pragma unroll
    for (int j = 0; j < 4; j++)
      #pragma unroll
      for (int rg = 0; rg < 4; rg++){
        size_t row = m0 + wm + i * 16 + quad * 4 + rg;
        int col = n0 + wn + j * 16 + lr;
        C[row * D_ + col] = acc[i][j][rg] + bias[col];
      }
}

// ---------------------------------------------------------------------------
// Causal score tiles: S[b][i][j] = (q_i . k_j)/32, fp32, 128x128 tiles.
// Grid (32, 32, 4) = (jt, it, b); jt > it exits early. Diagonal masks j > i.
// BK=128 + swizzle (round-10).
// ---------------------------------------------------------------------------
__global__ __launch_bounds__(256, 2)
void scores_gemm(){
  int jt = blockIdx.x, it = blockIdx.y, b = blockIdx.z;
  if (jt > it) return;
  __shared__ unsigned short __align__(16) As[128 * 128];   // 32 KiB
  __shared__ unsigned short __align__(16) Bs[128 * 128];   // 32 KiB
  int tid = threadIdx.x;
  size_t am0 = (size_t)b * N_ + it * 128;   // Q rows (global)
  size_t bn0 = (size_t)b * N_ + jt * 128;   // K rows (global)
  int l = tid & 63, wid = tid >> 6;
  int wm = (wid >> 1) * 64, wn = (wid & 1) * 64;
  int quad = l >> 4, lr = l & 15;
  floatx4 acc[4][4];
  #pragma unroll
  for (int i = 0; i < 4; i++)
    #pragma unroll
    for (int j = 0; j < 4; j++) acc[i][j] = (floatx4)0.0f;

  for (int k0 = 0; k0 < D_; k0 += 128){
    #pragma unroll
    for (int c = 0; c < 8; c++){
      int d = c * 4096 + tid * 16;
      int rw = d >> 8;
      int sc = ((d & 255) ^ ((rw & 7) << 4)) >> 1;
      gl_lds16(&g_Qb[(am0 + rw) * D_ + k0 + sc], &As[d >> 1]);
      gl_lds16(&g_Kb[(bn0 + rw) * D_ + k0 + sc], &Bs[d >> 1]);
    }
    __syncthreads();
    #pragma unroll
    for (int kk = 0; kk < 4; kk++){
      short8 af[4], bf[4];
      #pragma unroll
      for (int i = 0; i < 4; i++){
        int rw = wm + i * 16 + lr;
        int byt = rw * 256 + ((kk * 64 + quad * 16) ^ ((rw & 7) << 4));
        af[i] = *(const short8*)&As[byt >> 1];
      }
      #pragma unroll
      for (int j = 0; j < 4; j++){
        int rw = wn + j * 16 + lr;
        int byt = rw * 256 + ((kk * 64 + quad * 16) ^ ((rw & 7) << 4));
        bf[j] = *(const short8*)&Bs[byt >> 1];
      }
      #pragma unroll
      for (int i = 0; i < 4; i++)
        #pragma unroll
        for (int j = 0; j < 4; j++)
          acc[i][j] = __builtin_amdgcn_mfma_f32_16x16x32_bf16(af[i], bf[j], acc[i][j], 0, 0, 0);
    }
    __syncthreads();
  }
  #pragma unroll
  for (int i = 0; i < 4; i++)
    #pragma unroll
    for (int j = 0; j < 4; j++)
      #pragma unroll
      for (int rg = 0; rg < 4; rg++){
        int row = it * 128 + wm + i * 16 + quad * 4 + rg;   // in-batch
        int col = jt * 128 + wn + j * 16 + lr;
        float v = acc[i][j][rg] * 0.03125f;
        if (col > row) v = -3.0e38f;
        g_S[((size_t)b * N_ + row) * N_ + col] = v;
      }
}

// ---------------------------------------------------------------------------
// Per-row top-12 of causal scores. One wave per row (4 rows/block).
// ---------------------------------------------------------------------------
__global__ __launch_bounds__(256)
void row_topk(){
  __shared__ float lv[CAND * 256];   // [u][wave*64+lane]
  __shared__ int   li[CAND * 256];
  int w = threadIdx.x >> 6, l = threadIdx.x & 63;
  int g = threadIdx.x;
  int i = blockIdx.x * 4 + w;               // global row
  int irow = i & (N_ - 1);                  // in-batch row
  const float* Srow = &g_S[(size_t)i * N_];
  #pragma unroll
  for (int u = 0; u < CAND; u++){ lv[u * 256 + g] = -3.0e38f; li[u * 256 + g] = -1; }
  float vmin = -3.0e38f; int pmin = 0;
  for (int j0 = l * 4; j0 <= irow; j0 += 256){
    float4 v4 = *(const float4*)&Srow[j0];
    #pragma unroll
    for (int e = 0; e < 4; e++){
      float v = (&v4.x)[e];
      if (v > vmin){
        lv[pmin * 256 + g] = v; li[pmin * 256 + g] = j0 + e;
        float m = lv[g]; int p = 0;
        #pragma unroll
        for (int u = 1; u < CAND; u++){ float x = lv[u * 256 + g]; if (x < m){ m = x; p = u; } }
        vmin = m; pmin = p;
      }
    }
  }
  float mv = lv[g]; int mp = 0;
  #pragma unroll
  for (int u = 1; u < CAND; u++){ float x = lv[u * 256 + g]; if (x > mv){ mv = x; mp = u; } }
  int mj = li[mp * 256 + g];
  for (int rd = 0; rd < CAND; rd++){
    float bv = mv; int bj = mj; int bl = l;
    #pragma unroll
    for (int off = 32; off >= 1; off >>= 1){
      float ov = __shfl_xor(bv, off);
      int oj = __shfl_xor(bj, off);
      int ol = __shfl_xor(bl, off);
      if (ov > bv || (ov == bv && ol < bl)){ bv = ov; bj = oj; bl = ol; }
    }
    bool valid = (bv > -2.9e38f);
    if (l == 0) g_cand[(size_t)i * CAND + rd] = valid ? bj : -1;
    if (valid && bl == l){
      lv[mp * 256 + g] = -3.0e38f;
      mv = lv[g]; mp = 0;
      #pragma unroll
      for (int u = 1; u < CAND; u++){ float x = lv[u * 256 + g]; if (x > mv){ mv = x; mp = u; } }
      mj = li[mp * 256 + g];
    }
  }
}

// ---------------------------------------------------------------------------
// Fused: fp32 rescore of 12 candidates -> top-8 + softmax weights (in LDS)
// -> attn_out[i] = sum_r w_r * v[idx_r] (fp32 accumulate, bf16 out).
// fp32 dot noise ~5e-6 rel < 1.2e-5 split-GEMM method error. Each wave
// handles 3 candidates with interleaved loads (48 in flight) + 3 parallel
// FMA chains, then 3 interleaved shfl reductions.
// ---------------------------------------------------------------------------
__global__ __launch_bounds__(256)
void rescore_gather(){
  int i = blockIdx.x;
  int b = i >> 12;
  int tid = threadIdx.x, l = tid & 63, w = tid >> 6;
  __shared__ float cs[CAND];
  __shared__ int cid[CAND];
  __shared__ float ws8[8];
  __shared__ int id8[8];
  if (tid < CAND) cid[tid] = g_cand[(size_t)i * CAND + tid];
  __syncthreads();
  float q[16];
  #pragma unroll
  for (int u = 0; u < 16; u++) q[u] = g_Qf[(size_t)i * D_ + l + 64 * u];
  {
    int c0 = w * 3;
    int j0 = cid[c0], j1 = cid[c0 + 1], j2 = cid[c0 + 2];
    size_t k0o = ((size_t)(b * N_ + (j0 < 0 ? 0 : j0))) * D_;
    size_t k1o = ((size_t)(b * N_ + (j1 < 0 ? 0 : j1))) * D_;
    size_t k2o = ((size_t)(b * N_ + (j2 < 0 ? 0 : j2))) * D_;
    float a0 = 0.f, a1 = 0.f, a2 = 0.f;
    #pragma unroll
    for (int u = 0; u < 16; u++){
      float k0v = g_Kf[k0o + l + 64 * u];
      float k1v = g_Kf[k1o + l + 64 * u];
      float k2v = g_Kf[k2o + l + 64 * u];
      a0 = fmaf(q[u], k0v, a0);
      a1 = fmaf(q[u], k1v, a1);
      a2 = fmaf(q[u], k2v, a2);
    }
    #pragma unroll
    for (int off = 32; off >= 1; off >>= 1){
      a0 += __shfl_down(a0, off);
      a1 += __shfl_down(a1, off);
      a2 += __shfl_down(a2, off);
    }
    if (l == 0){
      cs[c0]     = (j0 >= 0) ? a0 * 0.03125f : -3.0e38f;
      cs[c0 + 1] = (j1 >= 0) ? a1 * 0.03125f : -3.0e38f;
      cs[c0 + 2] = (j2 >= 0) ? a2 * 0.03125f : -3.0e38f;
    }
  }
  __syncthreads();
  if (tid == 0){
    float v8[8]; int i8[8];
    bool used[CAND];
    for (int u = 0; u < CAND; u++) used[u] = false;
    for (int rk = 0; rk < 8; rk++){
      float best = -3.0e38f; int bp = -1;
      for (int c = 0; c < CAND; c++)
        if (!used[c] && cid[c] >= 0 && cs[c] > best){ best = cs[c]; bp = c; }
      if (bp >= 0){ used[bp] = true; v8[rk] = best; i8[rk] = cid[bp]; }
      else { v8[rk] = -3.0e38f; i8[rk] = -1; }
    }
    if (i8[0] < 0){ i8[0] = i & (N_ - 1); v8[0] = 0.0f; }   // never expected
    float mx = v8[0];
    float e[8]; float Z = 0.0f;
    for (int rk = 0; rk < 8; rk++){
      e[rk] = (i8[rk] >= 0) ? expf(v8[rk] - mx) : 0.0f;
      Z += e[rk];
    }
    for (int rk = 0; rk < 8; rk++){
      id8[rk] = i8[rk];
      ws8[rk] = e[rk] / Z;
    }
  }
  __syncthreads();
  int d0 = tid * 4;
  float a0 = 0.f, a1 = 0.f, a2 = 0.f, a3 = 0.f;
  #pragma unroll
  for (int rk = 0; rk < 8; rk++){
    int j = id8[rk];
    if (j < 0) continue;
    float wgt = ws8[rk];
    float4 vv = *(const float4*)&g_Vf[((size_t)(b * N_ + j)) * D_ + d0];
    a0 += wgt * vv.x; a1 += wgt * vv.y; a2 += wgt * vv.z; a3 += wgt * vv.w;
  }
  ushort4 o;
  o.x = f2b(a0); o.y = f2b(a1); o.z = f2b(a2); o.w = f2b(a3);
  *(ushort4*)&g_AO[(size_t)i * D_ + d0] = o;
}

// ---------------------------------------------------------------------------
extern "C" void kernel_launch(void* const* d_in, const int* in_sizes, int n_in,
                              void* d_out, int out_size, void* d_ws, size_t ws_size,
                              hipStream_t stream){
  const float* S  = (const float*)d_in[0];
  const float* Wq = (const float*)d_in[1];
  const float* bq = (const float*)d_in[2];
  const float* Wk = (const float*)d_in[3];
  const float* bk = (const float*)d_in[4];
  const float* Wv = (const float*)d_in[5];
  const float* bv = (const float*)d_in[6];
  const float* Wo = (const float*)d_in[7];
  const float* bo = (const float*)d_in[8];
  float* out = (float*)d_out;
  (void)d_ws; (void)ws_size; (void)in_sizes; (void)n_in; (void)out_size;

  transpose2<<<dim3(32, 32, 2), dim3(32, 8), 0, stream>>>(Wv, Wo);
  split_wT<<<dim3(32, 32, 2), dim3(32, 8), 0, stream>>>(Wq, Wk);
  split_x<<<dim3(M_), 256, 0, stream>>>(S);   // M_ blocks * 1024 elems = MD_
  qk_split_gemm<<<dim3(2048), 256, 0, stream>>>(bq, bk);
  gemm_bf16<<<dim3(1024), 256, 0, stream>>>(bv, nullptr, 0);
  scores_gemm<<<dim3(32, 32, 4), 256, 0, stream>>>();
  row_topk<<<dim3(M_ / 4), 256, 0, stream>>>();
  rescore_gather<<<dim3(M_), 256, 0, stream>>>();
  gemm_bf16<<<dim3(1024), 256, 0, stream>>>(bo, out, 1);
}